// Round 3
// baseline (1762.195 us; speedup 1.0000x reference)
//
#include <hip/hip_runtime.h>
#include <hip/hip_bf16.h>
#include <stdint.h>

#define N_NODES 100000
#define N_EDGES 3200000
#define ALPHA   0.1f
#define EB      128      // edges per propA block

typedef __attribute__((ext_vector_type(8))) short v8s;   // 8 x bf16
typedef __attribute__((ext_vector_type(4))) float f32x4; // MFMA acc

__device__ __forceinline__ uint32_t bf16_rne(float f) {
    uint32_t u = __float_as_uint(f);
    return (u + 0x7FFFu + ((u >> 16) & 1u)) >> 16;
}
__device__ __forceinline__ float bf16_f32(uint32_t b) { return __uint_as_float(b << 16); }

// ---------------------------------------------------------------------------
// W1 [256][512] fp32 -> A-fragment-ordered hi/lo bf16 chunks in global:
// chunk index = ((ks*2 + p)*16 + T)*64 + l ; content = W1[T*16 + (l&15)]
// [k = ks*32 + (l>>4)*8 .. +7], p=0 hi, p=1 lo. 32768 chunks x 16B = 512 KB.
// ---------------------------------------------------------------------------
__global__ __launch_bounds__(256) void w1_frag_kernel(
    const float* __restrict__ W1, uint4* __restrict__ W1f)
{
    int tid = blockIdx.x * 256 + threadIdx.x;   // 16384
    int ks = tid >> 10, T = (tid >> 6) & 15, l = tid & 63;
    int row = T * 16 + (l & 15);
    int kb  = ks * 32 + (l >> 4) * 8;
    const float* src = W1 + (size_t)row * 512 + kb;
    float4 f0 = *(const float4*)(src);
    float4 f1 = *(const float4*)(src + 4);
    float f[8] = {f0.x, f0.y, f0.z, f0.w, f1.x, f1.y, f1.z, f1.w};
    uint32_t hi[8], lo[8];
#pragma unroll
    for (int j = 0; j < 8; ++j) {
        hi[j] = bf16_rne(f[j]);
        lo[j] = bf16_rne(f[j] - bf16_f32(hi[j]));
    }
    uint4 H = make_uint4(hi[0] | (hi[1] << 16), hi[2] | (hi[3] << 16),
                         hi[4] | (hi[5] << 16), hi[6] | (hi[7] << 16));
    uint4 L = make_uint4(lo[0] | (lo[1] << 16), lo[2] | (lo[3] << 16),
                         lo[4] | (lo[5] << 16), lo[6] | (lo[7] << 16));
    size_t base = ((size_t)(ks * 2) * 16 + T) * 64 + l;
    W1f[base]        = H;
    W1f[base + 1024] = L;   // p=1 plane
}

// ---------------------------------------------------------------------------
// MLP: h = relu(x@W1^T+b1)@W2^T+b2 via MFMA 16x16x32 bf16 hi/lo split.
// Block 256 thr (4 waves), 64 nodes. Waves split hidden: wave w owns m-tiles
// w*4..w*4+3 (64 hidden) x all 4 n-tiles (64 nodes) -> acc 64 AGPR.
// W1 A-frags loaded straight from global frag image (L2); x staged in LDS
// (8 KB/slab) in B-frag order. GEMM2 in fp32 regs + shfl + LDS reduce.
// Also writes hs = dinv*h (pre-scaled z0 for propagation).
// ---------------------------------------------------------------------------
__global__ __launch_bounds__(256, 2) void mlp_kernel(
    const float* __restrict__ x, const uint4* __restrict__ W1f,
    const float* __restrict__ b1, const float* __restrict__ W2,
    const float* __restrict__ b2, const float* __restrict__ dinv,
    float* __restrict__ h, float* __restrict__ hs, int n)
{
    __shared__ __align__(16) char smem[33280];
    char*  xs   = smem;                    // K-loop: hi plane 4096 + lo plane 4096
    float* W2s  = (float*)smem;            // epilogue: [16][260] = 16640 B
    float* part = (float*)(smem + 16640);  // epilogue: [4][64][16] = 16384 B

    const int tid = threadIdx.x;
    const int w = tid >> 6, l = tid & 63;
    const int l15 = l & 15, q = l >> 4;
    const int row0 = blockIdx.x * 64;

    // staging ids: quarter-waves cover 16 nodes at same k-seg (coalesced + bank-clean)
    const int s_l15 = tid & 15;
    const int s_seg = (tid >> 4) & 3;
    const int s_u   = tid >> 6;
    const int s_grow = row0 + s_u * 16 + s_l15;

    f32x4 acc[4][4];
#pragma unroll
    for (int mt = 0; mt < 4; ++mt)
#pragma unroll
        for (int nt = 0; nt < 4; ++nt) acc[mt][nt] = (f32x4){0.f, 0.f, 0.f, 0.f};

    for (int ks = 0; ks < 16; ++ks) {
        // W1 A-frags: straight from global (L2-resident), no LDS
        uint4 aHu[4], aLu[4];
#pragma unroll
        for (int mt = 0; mt < 4; ++mt) {
            size_t cidx = ((size_t)(ks * 2) * 16 + (w * 4 + mt)) * 64 + l;
            aHu[mt] = W1f[cidx];
            aLu[mt] = W1f[cidx + 1024];
        }
        // x slab -> hi/lo -> LDS (B-frag order)
        float4 f0 = make_float4(0.f, 0.f, 0.f, 0.f), f1 = f0;
        if (s_grow < n) {
            const float* xp = x + (size_t)s_grow * 512 + ks * 32 + s_seg * 8;
            f0 = *(const float4*)(xp);
            f1 = *(const float4*)(xp + 4);
        }
        float f[8] = {f0.x, f0.y, f0.z, f0.w, f1.x, f1.y, f1.z, f1.w};
        uint32_t hi[8], lo[8];
#pragma unroll
        for (int j = 0; j < 8; ++j) {
            hi[j] = bf16_rne(f[j]);
            lo[j] = bf16_rne(f[j] - bf16_f32(hi[j]));
        }
        uint4 H = make_uint4(hi[0] | (hi[1] << 16), hi[2] | (hi[3] << 16),
                             hi[4] | (hi[5] << 16), hi[6] | (hi[7] << 16));
        uint4 L = make_uint4(lo[0] | (lo[1] << 16), lo[2] | (lo[3] << 16),
                             lo[4] | (lo[5] << 16), lo[6] | (lo[7] << 16));
        __syncthreads();   // prev iter's B-frag reads complete
        *(uint4*)(xs +        s_u * 1024 + (s_seg * 16 + s_l15) * 16) = H;
        *(uint4*)(xs + 4096 + s_u * 1024 + (s_seg * 16 + s_l15) * 16) = L;
        __syncthreads();

        v8s bH[4], bL[4];
#pragma unroll
        for (int nt = 0; nt < 4; ++nt) {
            bH[nt] = *(v8s*)(xs +        nt * 1024 + l * 16);
            bL[nt] = *(v8s*)(xs + 4096 + nt * 1024 + l * 16);
        }
#pragma unroll
        for (int mt = 0; mt < 4; ++mt) {
            v8s aH = *(v8s*)&aHu[mt];
            v8s aL = *(v8s*)&aLu[mt];
#pragma unroll
            for (int nt = 0; nt < 4; ++nt) {
                f32x4 c = acc[mt][nt];
                c = __builtin_amdgcn_mfma_f32_16x16x32_bf16(aH, bH[nt], c, 0, 0, 0);
                c = __builtin_amdgcn_mfma_f32_16x16x32_bf16(aH, bL[nt], c, 0, 0, 0);
                c = __builtin_amdgcn_mfma_f32_16x16x32_bf16(aL, bH[nt], c, 0, 0, 0);
                acc[mt][nt] = c;
            }
        }
    }

    // bias + relu: hidden = w*64 + mt*16 + q*4 + r ; node = nt*16 + l15
#pragma unroll
    for (int mt = 0; mt < 4; ++mt) {
        float4 bv = *(const float4*)(b1 + w * 64 + mt * 16 + q * 4);
#pragma unroll
        for (int nt = 0; nt < 4; ++nt) {
            acc[mt][nt][0] = fmaxf(acc[mt][nt][0] + bv.x, 0.f);
            acc[mt][nt][1] = fmaxf(acc[mt][nt][1] + bv.y, 0.f);
            acc[mt][nt][2] = fmaxf(acc[mt][nt][2] + bv.z, 0.f);
            acc[mt][nt][3] = fmaxf(acc[mt][nt][3] + bv.w, 0.f);
        }
    }

    __syncthreads();   // K-loop LDS dead; overlay W2s/part
    {
        int c = tid >> 4, k16 = (tid & 15) * 16;
#pragma unroll
        for (int i = 0; i < 4; ++i)
            *(float4*)(W2s + c * 260 + k16 + i * 4) =
                *(const float4*)(W2 + c * 256 + k16 + i * 4);
    }
    __syncthreads();

    float p[4][16];
#pragma unroll
    for (int nt = 0; nt < 4; ++nt)
#pragma unroll
        for (int c = 0; c < 16; ++c) p[nt][c] = 0.f;
#pragma unroll
    for (int c = 0; c < 16; ++c)
#pragma unroll
        for (int mt = 0; mt < 4; ++mt) {
            float4 wv = *(float4*)(W2s + c * 260 + w * 64 + mt * 16 + q * 4);
#pragma unroll
            for (int nt = 0; nt < 4; ++nt)
                p[nt][c] += acc[mt][nt][0] * wv.x + acc[mt][nt][1] * wv.y +
                            acc[mt][nt][2] * wv.z + acc[mt][nt][3] * wv.w;
        }
#pragma unroll
    for (int nt = 0; nt < 4; ++nt)
#pragma unroll
        for (int c = 0; c < 16; ++c) {
            p[nt][c] += __shfl_xor(p[nt][c], 16);
            p[nt][c] += __shfl_xor(p[nt][c], 32);
        }
#pragma unroll
    for (int nt = 0; nt < 4; ++nt) {
        float4 o;
        o.x = (q < 2) ? ((q == 0) ? p[nt][0] : p[nt][4]) : ((q == 2) ? p[nt][8]  : p[nt][12]);
        o.y = (q < 2) ? ((q == 0) ? p[nt][1] : p[nt][5]) : ((q == 2) ? p[nt][9]  : p[nt][13]);
        o.z = (q < 2) ? ((q == 0) ? p[nt][2] : p[nt][6]) : ((q == 2) ? p[nt][10] : p[nt][14]);
        o.w = (q < 2) ? ((q == 0) ? p[nt][3] : p[nt][7]) : ((q == 2) ? p[nt][11] : p[nt][15]);
        *(float4*)(part + ((w * 64 + nt * 16 + l15) << 4) + q * 4) = o;
    }
    __syncthreads();
    {
        int node = tid >> 2, c4 = (tid & 3) * 4;
        float4 s = make_float4(0.f, 0.f, 0.f, 0.f);
#pragma unroll
        for (int ww = 0; ww < 4; ++ww) {
            float4 v = *(float4*)(part + ((ww * 64 + node) << 4) + c4);
            s.x += v.x; s.y += v.y; s.z += v.z; s.w += v.w;
        }
        float4 bv = *(const float4*)(b2 + c4);
        int grow = row0 + node;
        if (grow < n) {
            float4 hv = make_float4(s.x + bv.x, s.y + bv.y, s.z + bv.z, s.w + bv.w);
            *(float4*)(h + (size_t)grow * 16 + c4) = hv;
            float di = dinv[grow];
            *(float4*)(hs + (size_t)grow * 16 + c4) =
                make_float4(di * hv.x, di * hv.y, di * hv.z, di * hv.w);
        }
    }
}

// ---------------------------------------------------------------------------
// CSR build
// ---------------------------------------------------------------------------
__global__ void hist_kernel(const int* __restrict__ dst, int* __restrict__ cnt, int e)
{
    int i = blockIdx.x * blockDim.x + threadIdx.x;
    if (i < e) atomicAdd(&cnt[dst[i]], 1);
}

__global__ void dinv_kernel(const int* __restrict__ cnt, float* __restrict__ dinv, int n)
{
    int i = blockIdx.x * blockDim.x + threadIdx.x;
    if (i < n) dinv[i] = rsqrtf((float)cnt[i] + 1.0f);  // +1 self-loop
}

// multi-block exclusive scan (3 phases)
__global__ __launch_bounds__(256) void scan1_kernel(
    const int* __restrict__ cnt, int* __restrict__ row_loc,
    int* __restrict__ bsum, int n)
{
    __shared__ int sm[256];
    int i = blockIdx.x * 256 + threadIdx.x;
    int v = (i < n) ? cnt[i] : 0;
    sm[threadIdx.x] = v;
    __syncthreads();
#pragma unroll
    for (int off = 1; off < 256; off <<= 1) {
        int t = (threadIdx.x >= off) ? sm[threadIdx.x - off] : 0;
        __syncthreads();
        sm[threadIdx.x] += t;
        __syncthreads();
    }
    if (i < n) row_loc[i] = sm[threadIdx.x] - v;          // local exclusive
    if (threadIdx.x == 255) bsum[blockIdx.x] = sm[255];   // block total
}

__global__ __launch_bounds__(512) void scan2_kernel(
    const int* __restrict__ bsum, int* __restrict__ boff, int nb)
{
    __shared__ int sm[512];
    int i = threadIdx.x;
    int v = (i < nb) ? bsum[i] : 0;
    sm[i] = v;
    __syncthreads();
#pragma unroll
    for (int off = 1; off < 512; off <<= 1) {
        int t = (i >= off) ? sm[i - off] : 0;
        __syncthreads();
        sm[i] += t;
        __syncthreads();
    }
    if (i < nb) boff[i] = sm[i] - v;   // exclusive
}

__global__ void scan3_kernel(int* __restrict__ row_st, const int* __restrict__ boff,
                             int* __restrict__ cursor, int n, int e)
{
    int i = blockIdx.x * blockDim.x + threadIdx.x;
    if (i < n) {
        int r = row_st[i] + boff[i >> 8];
        row_st[i] = r;
        cursor[i] = r;
    }
    if (i == 0) row_st[n] = e;
}

__global__ void scatter_kernel(
    const int* __restrict__ src, const int* __restrict__ dst,
    int* __restrict__ cursor, int2* __restrict__ csr_sd, int e)
{
    int i = blockIdx.x * blockDim.x + threadIdx.x;
    if (i < e) {
        int s = src[i], d = dst[i];
        int pos = atomicAdd(&cursor[d], 1);
        csr_sd[pos] = make_int2(s, d);
    }
}

// ---------------------------------------------------------------------------
// Propagation, edge-parallel, atomic-free. zs = dinv*z flows between steps.
// propA: 128 dst-sorted edges/block, 4 lanes/edge (float4 classes). Segment
// sums from LDS with trip counts known from row_start. Full-run nodes
// finalized in-block; boundary-crossing runs -> per-block spill slots.
// ---------------------------------------------------------------------------
__device__ __forceinline__ void finalize_node(
    int d, float4 S, const float* dinv, const float* zs_in, const float* hmat,
    float* out, int f4, int is_last)
{
    float di = dinv[d];
    const float4 self = *(const float4*)(zs_in + (size_t)d * 16 + f4);
    const float4 hv   = *(const float4*)(hmat + (size_t)d * 16 + f4);
    float4 zn;
    zn.x = fmaf(1.0f - ALPHA, di * (S.x + self.x), ALPHA * hv.x);
    zn.y = fmaf(1.0f - ALPHA, di * (S.y + self.y), ALPHA * hv.y);
    zn.z = fmaf(1.0f - ALPHA, di * (S.z + self.z), ALPHA * hv.z);
    zn.w = fmaf(1.0f - ALPHA, di * (S.w + self.w), ALPHA * hv.w);
    if (!is_last) {
        *(float4*)(out + (size_t)d * 16 + f4) =
            make_float4(di * zn.x, di * zn.y, di * zn.z, di * zn.w);
    } else {
        float m = fmaxf(fmaxf(zn.x, zn.y), fmaxf(zn.z, zn.w));
        m = fmaxf(m, __shfl_xor(m, 1));
        m = fmaxf(m, __shfl_xor(m, 2));
        float ss = expf(zn.x - m) + expf(zn.y - m) + expf(zn.z - m) + expf(zn.w - m);
        ss += __shfl_xor(ss, 1);
        ss += __shfl_xor(ss, 2);
        float ls = logf(ss);
        *(float4*)(out + (size_t)d * 16 + f4) =
            make_float4(zn.x - m - ls, zn.y - m - ls, zn.z - m - ls, zn.w - m - ls);
    }
}

__global__ __launch_bounds__(512) void propA_kernel(
    const int2* __restrict__ csr_sd, const int* __restrict__ row_st,
    const float* __restrict__ dinv, const float* __restrict__ zs_in,
    const float* __restrict__ hmat, float* __restrict__ out,
    int* __restrict__ spF_id, int* __restrict__ spB_id,
    float* __restrict__ spF_v, float* __restrict__ spB_v, int is_last)
{
    __shared__ float sc[EB * 16];   // 8 KB contributions
    const int tid = threadIdx.x;
    const int quad = tid >> 2;
    const int f4 = (tid & 3) * 4;
    const int blk_lo = blockIdx.x * EB;
    const int j = blk_lo + quad;

    int d = -1;
    float4 c4 = make_float4(0.f, 0.f, 0.f, 0.f);
    if (j < N_EDGES) {
        int2 sd = csr_sd[j];
        d = sd.y;
        c4 = *(const float4*)(zs_in + (size_t)sd.x * 16 + f4);
    }
    *(float4*)(sc + quad * 16 + f4) = c4;
    __syncthreads();
    if (j >= N_EDGES) return;

    const int rs = row_st[d];
    const bool is_start = (quad == 0) || (j == rs);
    if (!is_start) return;

    const int re = row_st[d + 1];
    const int kend = min(re - blk_lo, EB);    // local end of this run
    float4 S = c4;
    for (int k = quad + 1; k < kend; ++k) {
        S.x += sc[k * 16 + f4 + 0];
        S.y += sc[k * 16 + f4 + 1];
        S.z += sc[k * 16 + f4 + 2];
        S.w += sc[k * 16 + f4 + 3];
    }
    const int run_e = blk_lo + kend;
    const bool full = (j == rs) && (run_e == re);
    const bool first_run = (quad == 0);
    const bool last_run  = (kend == EB) || (run_e == N_EDGES);

    if (full)
        finalize_node(d, S, dinv, zs_in, hmat, out, f4, is_last);

    if (first_run) {
        if ((tid & 3) == 0) {
            spF_id[blockIdx.x] = full ? -1 : d;
            if (last_run) spB_id[blockIdx.x] = -1;   // single-run block
        }
        if (!full) *(float4*)(spF_v + blockIdx.x * 16 + f4) = S;
    } else if (last_run) {
        if ((tid & 3) == 0) spB_id[blockIdx.x] = full ? -1 : d;
        if (!full) *(float4*)(spB_v + blockIdx.x * 16 + f4) = S;
    }
}

// fixup: nodes whose edge range crosses a 128-edge block boundary (or deg 0)
__global__ __launch_bounds__(256) void propB_kernel(
    const int* __restrict__ row_st, const float* __restrict__ dinv,
    const float* __restrict__ zs_in, const float* __restrict__ hmat,
    float* __restrict__ out,
    const int* __restrict__ spF_id, const int* __restrict__ spB_id,
    const float* __restrict__ spF_v, const float* __restrict__ spB_v,
    int n, int is_last)
{
    const int d = blockIdx.x * 64 + (threadIdx.x >> 2);
    const int f4 = (threadIdx.x & 3) * 4;
    if (d >= n) return;
    const int rs = row_st[d], re = row_st[d + 1];
    const bool crossing = (rs == re) || ((rs >> 7) != ((re - 1) >> 7));
    if (!crossing) return;   // handled by propA
    float4 S = make_float4(0.f, 0.f, 0.f, 0.f);
    if (re > rs) {
        const int b0 = rs >> 7, b1 = (re - 1) >> 7;
        for (int b = b0; b <= b1; ++b) {
            if (spF_id[b] == d) {
                S.x += spF_v[b * 16 + f4 + 0]; S.y += spF_v[b * 16 + f4 + 1];
                S.z += spF_v[b * 16 + f4 + 2]; S.w += spF_v[b * 16 + f4 + 3];
            }
            if (spB_id[b] == d) {
                S.x += spB_v[b * 16 + f4 + 0]; S.y += spB_v[b * 16 + f4 + 1];
                S.z += spB_v[b * 16 + f4 + 2]; S.w += spB_v[b * 16 + f4 + 3];
            }
        }
    }
    finalize_node(d, S, dinv, zs_in, hmat, out, f4, is_last);
}

// ---------------------------------------------------------------------------
extern "C" void kernel_launch(void* const* d_in, const int* in_sizes, int n_in,
                              void* d_out, int out_size, void* d_ws, size_t ws_size,
                              hipStream_t stream)
{
    const float* x  = (const float*)d_in[0];
    const float* W1 = (const float*)d_in[1];
    const float* b1 = (const float*)d_in[2];
    const float* W2 = (const float*)d_in[3];
    const float* b2 = (const float*)d_in[4];
    const int*   ei = (const int*)d_in[5];

    const int N = N_NODES;
    const int E = N_EDGES;
    const int* srcp = ei;
    const int* dstp = ei + E;

    float* ws = (float*)d_ws;
    // persistent regions
    float* h       = ws;                        // 1,600,000 f
    float* ZSA     = ws + 1600000;              // 1,600,000 f
    float* ZSB     = ws + 3200000;              // 1,600,000 f  (starts as hs)
    float* dinv    = ws + 4800000;              // 100,000 f
    int*   row_st  = (int*)(ws + 4900000);      // 100,001 i (pad 100004)
    int2*  csr_sd  = (int2*)(ws + 5000004);     // 3,200,000 x 8B
    int*   spF_id  = (int*)(ws + 11400004);     // 25,000
    int*   spB_id  = (int*)(ws + 11425004);     // 25,000
    float* spF_v   = ws + 11450004;             // 400,000
    float* spB_v   = ws + 11850004;             // 400,000  -> end 12,250,004 f ~49 MB
    // transient overlays (dead before their hosts are written):
    int*   cnt     = (int*)(ws);                // in h region (h written after scatter)
    int*   cursor  = (int*)(ws + 100000);       // in h region
    int*   bsum    = (int*)(ws + 200000);       // in h region (512)
    int*   boff    = (int*)(ws + 200512);       // in h region (512)
    uint4* W1f     = (uint4*)(ws + 1600000);    // in ZSA region (dead before step 0)

    const int NB_SCAN = (N + 255) / 256;        // 391

    hipMemsetAsync(cnt, 0, (size_t)N * sizeof(int), stream);
    hist_kernel<<<(E + 255) / 256, 256, 0, stream>>>(dstp, cnt, E);
    dinv_kernel<<<(N + 255) / 256, 256, 0, stream>>>(cnt, dinv, N);
    scan1_kernel<<<NB_SCAN, 256, 0, stream>>>(cnt, row_st, bsum, N);
    scan2_kernel<<<1, 512, 0, stream>>>(bsum, boff, NB_SCAN);
    scan3_kernel<<<(N + 255) / 256, 256, 0, stream>>>(row_st, boff, cursor, N, E);
    scatter_kernel<<<(E + 255) / 256, 256, 0, stream>>>(srcp, dstp, cursor, csr_sd, E);
    w1_frag_kernel<<<64, 256, 0, stream>>>(W1, W1f);
    mlp_kernel<<<(N + 63) / 64, 256, 0, stream>>>(x, W1f, b1, W2, b2, dinv, h, ZSB, N);

    const int NPB = 25000;  // E / EB
    for (int k = 0; k < 10; ++k) {
        const int last = (k == 9) ? 1 : 0;
        const float* zin = (k == 0) ? ZSB : ((k & 1) ? ZSA : ZSB);
        float* zo = last ? (float*)d_out : ((k & 1) ? ZSB : ZSA);
        propA_kernel<<<NPB, 512, 0, stream>>>(csr_sd, row_st, dinv, zin, h, zo,
                                              spF_id, spB_id, spF_v, spB_v, last);
        propB_kernel<<<(N + 63) / 64, 256, 0, stream>>>(row_st, dinv, zin, h, zo,
                                                        spF_id, spB_id, spF_v, spB_v,
                                                        N, last);
    }
}

// Round 4
// 1620.357 us; speedup vs baseline: 1.0875x; 1.0875x over previous
//
#include <hip/hip_runtime.h>
#include <hip/hip_bf16.h>
#include <stdint.h>

#define N_NODES 100000
#define N_EDGES 3200000
#define ALPHA   0.1f
#define EB      128      // edges per propA block

typedef __attribute__((ext_vector_type(8))) short v8s;   // 8 x bf16
typedef __attribute__((ext_vector_type(4))) float f32x4; // MFMA acc

__device__ __forceinline__ uint32_t bf16_rne(float f) {
    uint32_t u = __float_as_uint(f);
    return (u + 0x7FFFu + ((u >> 16) & 1u)) >> 16;
}
__device__ __forceinline__ float bf16_f32(uint32_t b) { return __uint_as_float(b << 16); }

// ---------------------------------------------------------------------------
// W1 [256][512] fp32 -> A-fragment-ordered hi/lo bf16 chunks in global:
// chunk index = ((ks*2 + p)*16 + T)*64 + l ; content = W1[T*16 + (l&15)]
// [k = ks*32 + (l>>4)*8 .. +7], p=0 hi, p=1 lo. 32768 chunks x 16B = 512 KB.
// ---------------------------------------------------------------------------
__global__ __launch_bounds__(256) void w1_frag_kernel(
    const float* __restrict__ W1, uint4* __restrict__ W1f)
{
    int tid = blockIdx.x * 256 + threadIdx.x;   // 16384
    int ks = tid >> 10, T = (tid >> 6) & 15, l = tid & 63;
    int row = T * 16 + (l & 15);
    int kb  = ks * 32 + (l >> 4) * 8;
    const float* src = W1 + (size_t)row * 512 + kb;
    float4 f0 = *(const float4*)(src);
    float4 f1 = *(const float4*)(src + 4);
    float f[8] = {f0.x, f0.y, f0.z, f0.w, f1.x, f1.y, f1.z, f1.w};
    uint32_t hi[8], lo[8];
#pragma unroll
    for (int j = 0; j < 8; ++j) {
        hi[j] = bf16_rne(f[j]);
        lo[j] = bf16_rne(f[j] - bf16_f32(hi[j]));
    }
    uint4 H = make_uint4(hi[0] | (hi[1] << 16), hi[2] | (hi[3] << 16),
                         hi[4] | (hi[5] << 16), hi[6] | (hi[7] << 16));
    uint4 L = make_uint4(lo[0] | (lo[1] << 16), lo[2] | (lo[3] << 16),
                         lo[4] | (lo[5] << 16), lo[6] | (lo[7] << 16));
    size_t base = ((size_t)(ks * 2) * 16 + T) * 64 + l;
    W1f[base]        = H;
    W1f[base + 1024] = L;   // p=1 plane
}

// ---------------------------------------------------------------------------
// MLP: h = relu(x@W1^T+b1)@W2^T+b2 via MFMA 16x16x32 bf16 hi/lo split.
// Block 256 thr (4 waves), 64 nodes. Wave w owns hidden 64w..64w+63.
// W1 A-frags loaded straight from global frag image (L2); x staged in LDS
// in B-frag order. GEMM2 epilogue: 4-class chunks (p[4][4] live, NOT
// p[4][16] — R3's 64-float accumulator spilled ~410 MB to scratch).
// ---------------------------------------------------------------------------
__global__ __launch_bounds__(256, 2) void mlp_kernel(
    const float* __restrict__ x, const uint4* __restrict__ W1f,
    const float* __restrict__ b1, const float* __restrict__ W2,
    const float* __restrict__ b2, const float* __restrict__ dinv,
    float* __restrict__ h, float* __restrict__ hs, int n)
{
    __shared__ __align__(16) char smem[33280];
    char*  xs   = smem;                    // K-loop: hi plane 4096 + lo plane 4096
    float* W2s  = (float*)smem;            // epilogue: [16][260] = 16640 B
    float* part = (float*)(smem + 16640);  // epilogue: [4][64][16] = 16384 B

    const int tid = threadIdx.x;
    const int w = tid >> 6, l = tid & 63;
    const int l15 = l & 15, q = l >> 4;
    const int row0 = blockIdx.x * 64;

    // staging ids: quarter-waves cover 16 nodes at same k-seg (coalesced)
    const int s_l15 = tid & 15;
    const int s_seg = (tid >> 4) & 3;
    const int s_u   = tid >> 6;
    const int s_grow = row0 + s_u * 16 + s_l15;

    f32x4 acc[4][4];
#pragma unroll
    for (int mt = 0; mt < 4; ++mt)
#pragma unroll
        for (int nt = 0; nt < 4; ++nt) acc[mt][nt] = (f32x4){0.f, 0.f, 0.f, 0.f};

    for (int ks = 0; ks < 16; ++ks) {
        // W1 A-frags straight from global (L2-resident)
        uint4 aHu[4], aLu[4];
#pragma unroll
        for (int mt = 0; mt < 4; ++mt) {
            size_t cidx = ((size_t)(ks * 2) * 16 + (w * 4 + mt)) * 64 + l;
            aHu[mt] = W1f[cidx];
            aLu[mt] = W1f[cidx + 1024];
        }
        // x slab -> hi/lo -> LDS (B-frag order)
        float4 f0 = make_float4(0.f, 0.f, 0.f, 0.f), f1 = f0;
        if (s_grow < n) {
            const float* xp = x + (size_t)s_grow * 512 + ks * 32 + s_seg * 8;
            f0 = *(const float4*)(xp);
            f1 = *(const float4*)(xp + 4);
        }
        float f[8] = {f0.x, f0.y, f0.z, f0.w, f1.x, f1.y, f1.z, f1.w};
        uint32_t hi[8], lo[8];
#pragma unroll
        for (int j = 0; j < 8; ++j) {
            hi[j] = bf16_rne(f[j]);
            lo[j] = bf16_rne(f[j] - bf16_f32(hi[j]));
        }
        uint4 H = make_uint4(hi[0] | (hi[1] << 16), hi[2] | (hi[3] << 16),
                             hi[4] | (hi[5] << 16), hi[6] | (hi[7] << 16));
        uint4 L = make_uint4(lo[0] | (lo[1] << 16), lo[2] | (lo[3] << 16),
                             lo[4] | (lo[5] << 16), lo[6] | (lo[7] << 16));
        __syncthreads();   // prev iter's B-frag reads complete
        *(uint4*)(xs +        s_u * 1024 + (s_seg * 16 + s_l15) * 16) = H;
        *(uint4*)(xs + 4096 + s_u * 1024 + (s_seg * 16 + s_l15) * 16) = L;
        __syncthreads();

        v8s bH[4], bL[4];
#pragma unroll
        for (int nt = 0; nt < 4; ++nt) {
            bH[nt] = *(v8s*)(xs +        nt * 1024 + l * 16);
            bL[nt] = *(v8s*)(xs + 4096 + nt * 1024 + l * 16);
        }
#pragma unroll
        for (int mt = 0; mt < 4; ++mt) {
            v8s aH = *(v8s*)&aHu[mt];
            v8s aL = *(v8s*)&aLu[mt];
#pragma unroll
            for (int nt = 0; nt < 4; ++nt) {
                f32x4 c = acc[mt][nt];
                c = __builtin_amdgcn_mfma_f32_16x16x32_bf16(aH, bH[nt], c, 0, 0, 0);
                c = __builtin_amdgcn_mfma_f32_16x16x32_bf16(aH, bL[nt], c, 0, 0, 0);
                c = __builtin_amdgcn_mfma_f32_16x16x32_bf16(aL, bH[nt], c, 0, 0, 0);
                acc[mt][nt] = c;
            }
        }
    }

    // bias + relu: hidden = w*64 + mt*16 + q*4 + r ; node = nt*16 + l15
#pragma unroll
    for (int mt = 0; mt < 4; ++mt) {
        float4 bv = *(const float4*)(b1 + w * 64 + mt * 16 + q * 4);
#pragma unroll
        for (int nt = 0; nt < 4; ++nt) {
            acc[mt][nt][0] = fmaxf(acc[mt][nt][0] + bv.x, 0.f);
            acc[mt][nt][1] = fmaxf(acc[mt][nt][1] + bv.y, 0.f);
            acc[mt][nt][2] = fmaxf(acc[mt][nt][2] + bv.z, 0.f);
            acc[mt][nt][3] = fmaxf(acc[mt][nt][3] + bv.w, 0.f);
        }
    }

    __syncthreads();   // K-loop LDS dead; overlay W2s/part
    {
        int c = tid >> 4, k16 = (tid & 15) * 16;
#pragma unroll
        for (int i = 0; i < 4; ++i)
            *(float4*)(W2s + c * 260 + k16 + i * 4) =
                *(const float4*)(W2 + c * 256 + k16 + i * 4);
    }
    __syncthreads();

    // ---- GEMM2, 4-class chunks: live accumulator = p2[4][4] (16 floats) ----
#pragma unroll
    for (int c4 = 0; c4 < 4; ++c4) {
        float p2[4][4];
#pragma unroll
        for (int nt = 0; nt < 4; ++nt)
#pragma unroll
            for (int cc = 0; cc < 4; ++cc) p2[nt][cc] = 0.f;
#pragma unroll
        for (int mt = 0; mt < 4; ++mt)
#pragma unroll
            for (int cc = 0; cc < 4; ++cc) {
                float4 wv = *(float4*)(W2s + (c4 * 4 + cc) * 260 + w * 64 + mt * 16 + q * 4);
#pragma unroll
                for (int nt = 0; nt < 4; ++nt)
                    p2[nt][cc] += acc[mt][nt][0] * wv.x + acc[mt][nt][1] * wv.y +
                                  acc[mt][nt][2] * wv.z + acc[mt][nt][3] * wv.w;
            }
        // reduce over the 4 quads
#pragma unroll
        for (int nt = 0; nt < 4; ++nt)
#pragma unroll
            for (int cc = 0; cc < 4; ++cc) {
                p2[nt][cc] += __shfl_xor(p2[nt][cc], 16);
                p2[nt][cc] += __shfl_xor(p2[nt][cc], 32);
            }
        if (q == c4) {
#pragma unroll
            for (int nt = 0; nt < 4; ++nt)
                *(float4*)(part + ((w * 64 + nt * 16 + l15) << 4) + c4 * 4) =
                    make_float4(p2[nt][0], p2[nt][1], p2[nt][2], p2[nt][3]);
        }
    }
    __syncthreads();
    {
        int node = tid >> 2, c4 = (tid & 3) * 4;
        float4 s = make_float4(0.f, 0.f, 0.f, 0.f);
#pragma unroll
        for (int ww = 0; ww < 4; ++ww) {
            float4 v = *(float4*)(part + ((ww * 64 + node) << 4) + c4);
            s.x += v.x; s.y += v.y; s.z += v.z; s.w += v.w;
        }
        float4 bv = *(const float4*)(b2 + c4);
        int grow = row0 + node;
        if (grow < n) {
            float4 hv = make_float4(s.x + bv.x, s.y + bv.y, s.z + bv.z, s.w + bv.w);
            *(float4*)(h + (size_t)grow * 16 + c4) = hv;
            float di = dinv[grow];
            *(float4*)(hs + (size_t)grow * 16 + c4) =
                make_float4(di * hv.x, di * hv.y, di * hv.z, di * hv.w);
        }
    }
}

// ---------------------------------------------------------------------------
// CSR build
// ---------------------------------------------------------------------------
__global__ void hist_kernel(const int* __restrict__ dst, int* __restrict__ cnt, int e)
{
    int i = blockIdx.x * blockDim.x + threadIdx.x;
    if (i < e) atomicAdd(&cnt[dst[i]], 1);
}

__global__ void dinv_kernel(const int* __restrict__ cnt, float* __restrict__ dinv, int n)
{
    int i = blockIdx.x * blockDim.x + threadIdx.x;
    if (i < n) dinv[i] = rsqrtf((float)cnt[i] + 1.0f);  // +1 self-loop
}

// multi-block exclusive scan (3 phases)
__global__ __launch_bounds__(256) void scan1_kernel(
    const int* __restrict__ cnt, int* __restrict__ row_loc,
    int* __restrict__ bsum, int n)
{
    __shared__ int sm[256];
    int i = blockIdx.x * 256 + threadIdx.x;
    int v = (i < n) ? cnt[i] : 0;
    sm[threadIdx.x] = v;
    __syncthreads();
#pragma unroll
    for (int off = 1; off < 256; off <<= 1) {
        int t = (threadIdx.x >= off) ? sm[threadIdx.x - off] : 0;
        __syncthreads();
        sm[threadIdx.x] += t;
        __syncthreads();
    }
    if (i < n) row_loc[i] = sm[threadIdx.x] - v;          // local exclusive
    if (threadIdx.x == 255) bsum[blockIdx.x] = sm[255];   // block total
}

__global__ __launch_bounds__(512) void scan2_kernel(
    const int* __restrict__ bsum, int* __restrict__ boff, int nb)
{
    __shared__ int sm[512];
    int i = threadIdx.x;
    int v = (i < nb) ? bsum[i] : 0;
    sm[i] = v;
    __syncthreads();
#pragma unroll
    for (int off = 1; off < 512; off <<= 1) {
        int t = (i >= off) ? sm[i - off] : 0;
        __syncthreads();
        sm[i] += t;
        __syncthreads();
    }
    if (i < nb) boff[i] = sm[i] - v;   // exclusive
}

__global__ void scan3_kernel(int* __restrict__ row_st, const int* __restrict__ boff,
                             int* __restrict__ cursor, int n, int e)
{
    int i = blockIdx.x * blockDim.x + threadIdx.x;
    if (i < n) {
        int r = row_st[i] + boff[i >> 8];
        row_st[i] = r;
        cursor[i] = r;
    }
    if (i == 0) row_st[n] = e;
}

__global__ void scatter_kernel(
    const int* __restrict__ src, const int* __restrict__ dst,
    int* __restrict__ cursor, int2* __restrict__ csr_sd, int e)
{
    int i = blockIdx.x * blockDim.x + threadIdx.x;
    if (i < e) {
        int s = src[i], d = dst[i];
        int pos = atomicAdd(&cursor[d], 1);
        csr_sd[pos] = make_int2(s, d);
    }
}

// ---------------------------------------------------------------------------
// Propagation, edge-parallel, atomic-free. zs = dinv*z flows between steps.
// ---------------------------------------------------------------------------
__device__ __forceinline__ void finalize_node(
    int d, float4 S, const float* dinv, const float* zs_in, const float* hmat,
    float* out, int f4, int is_last)
{
    float di = dinv[d];
    const float4 self = *(const float4*)(zs_in + (size_t)d * 16 + f4);
    const float4 hv   = *(const float4*)(hmat + (size_t)d * 16 + f4);
    float4 zn;
    zn.x = fmaf(1.0f - ALPHA, di * (S.x + self.x), ALPHA * hv.x);
    zn.y = fmaf(1.0f - ALPHA, di * (S.y + self.y), ALPHA * hv.y);
    zn.z = fmaf(1.0f - ALPHA, di * (S.z + self.z), ALPHA * hv.z);
    zn.w = fmaf(1.0f - ALPHA, di * (S.w + self.w), ALPHA * hv.w);
    if (!is_last) {
        *(float4*)(out + (size_t)d * 16 + f4) =
            make_float4(di * zn.x, di * zn.y, di * zn.z, di * zn.w);
    } else {
        float m = fmaxf(fmaxf(zn.x, zn.y), fmaxf(zn.z, zn.w));
        m = fmaxf(m, __shfl_xor(m, 1));
        m = fmaxf(m, __shfl_xor(m, 2));
        float ss = expf(zn.x - m) + expf(zn.y - m) + expf(zn.z - m) + expf(zn.w - m);
        ss += __shfl_xor(ss, 1);
        ss += __shfl_xor(ss, 2);
        float ls = logf(ss);
        *(float4*)(out + (size_t)d * 16 + f4) =
            make_float4(zn.x - m - ls, zn.y - m - ls, zn.z - m - ls, zn.w - m - ls);
    }
}

__global__ __launch_bounds__(512) void propA_kernel(
    const int2* __restrict__ csr_sd, const int* __restrict__ row_st,
    const float* __restrict__ dinv, const float* __restrict__ zs_in,
    const float* __restrict__ hmat, float* __restrict__ out,
    int* __restrict__ spF_id, int* __restrict__ spB_id,
    float* __restrict__ spF_v, float* __restrict__ spB_v, int is_last)
{
    __shared__ float sc[EB * 16];   // 8 KB contributions
    const int tid = threadIdx.x;
    const int quad = tid >> 2;
    const int f4 = (tid & 3) * 4;
    const int blk_lo = blockIdx.x * EB;
    const int j = blk_lo + quad;

    int d = -1;
    float4 c4 = make_float4(0.f, 0.f, 0.f, 0.f);
    if (j < N_EDGES) {
        int2 sd = csr_sd[j];
        d = sd.y;
        c4 = *(const float4*)(zs_in + (size_t)sd.x * 16 + f4);
    }
    *(float4*)(sc + quad * 16 + f4) = c4;
    __syncthreads();
    if (j >= N_EDGES) return;

    const int rs = row_st[d];
    const bool is_start = (quad == 0) || (j == rs);
    if (!is_start) return;

    const int re = row_st[d + 1];
    const int kend = min(re - blk_lo, EB);    // local end of this run
    float4 S = c4;
    for (int k = quad + 1; k < kend; ++k) {
        S.x += sc[k * 16 + f4 + 0];
        S.y += sc[k * 16 + f4 + 1];
        S.z += sc[k * 16 + f4 + 2];
        S.w += sc[k * 16 + f4 + 3];
    }
    const int run_e = blk_lo + kend;
    const bool full = (j == rs) && (run_e == re);
    const bool first_run = (quad == 0);
    const bool last_run  = (kend == EB) || (run_e == N_EDGES);

    if (full)
        finalize_node(d, S, dinv, zs_in, hmat, out, f4, is_last);

    if (first_run) {
        if ((tid & 3) == 0) {
            spF_id[blockIdx.x] = full ? -1 : d;
            if (last_run) spB_id[blockIdx.x] = -1;   // single-run block
        }
        if (!full) *(float4*)(spF_v + blockIdx.x * 16 + f4) = S;
    } else if (last_run) {
        if ((tid & 3) == 0) spB_id[blockIdx.x] = full ? -1 : d;
        if (!full) *(float4*)(spB_v + blockIdx.x * 16 + f4) = S;
    }
}

// fixup: nodes whose edge range crosses a 128-edge block boundary (or deg 0)
__global__ __launch_bounds__(256) void propB_kernel(
    const int* __restrict__ row_st, const float* __restrict__ dinv,
    const float* __restrict__ zs_in, const float* __restrict__ hmat,
    float* __restrict__ out,
    const int* __restrict__ spF_id, const int* __restrict__ spB_id,
    const float* __restrict__ spF_v, const float* __restrict__ spB_v,
    int n, int is_last)
{
    const int d = blockIdx.x * 64 + (threadIdx.x >> 2);
    const int f4 = (threadIdx.x & 3) * 4;
    if (d >= n) return;
    const int rs = row_st[d], re = row_st[d + 1];
    const bool crossing = (rs == re) || ((rs >> 7) != ((re - 1) >> 7));
    if (!crossing) return;   // handled by propA
    float4 S = make_float4(0.f, 0.f, 0.f, 0.f);
    if (re > rs) {
        const int b0 = rs >> 7, b1 = (re - 1) >> 7;
        for (int b = b0; b <= b1; ++b) {
            if (spF_id[b] == d) {
                S.x += spF_v[b * 16 + f4 + 0]; S.y += spF_v[b * 16 + f4 + 1];
                S.z += spF_v[b * 16 + f4 + 2]; S.w += spF_v[b * 16 + f4 + 3];
            }
            if (spB_id[b] == d) {
                S.x += spB_v[b * 16 + f4 + 0]; S.y += spB_v[b * 16 + f4 + 1];
                S.z += spB_v[b * 16 + f4 + 2]; S.w += spB_v[b * 16 + f4 + 3];
            }
        }
    }
    finalize_node(d, S, dinv, zs_in, hmat, out, f4, is_last);
}

// ---------------------------------------------------------------------------
extern "C" void kernel_launch(void* const* d_in, const int* in_sizes, int n_in,
                              void* d_out, int out_size, void* d_ws, size_t ws_size,
                              hipStream_t stream)
{
    const float* x  = (const float*)d_in[0];
    const float* W1 = (const float*)d_in[1];
    const float* b1 = (const float*)d_in[2];
    const float* W2 = (const float*)d_in[3];
    const float* b2 = (const float*)d_in[4];
    const int*   ei = (const int*)d_in[5];

    const int N = N_NODES;
    const int E = N_EDGES;
    const int* srcp = ei;
    const int* dstp = ei + E;

    float* ws = (float*)d_ws;
    // persistent regions
    float* h       = ws;                        // 1,600,000 f
    float* ZSA     = ws + 1600000;              // 1,600,000 f
    float* ZSB     = ws + 3200000;              // 1,600,000 f  (starts as hs)
    float* dinv    = ws + 4800000;              // 100,000 f
    int*   row_st  = (int*)(ws + 4900000);      // 100,001 i (pad 100004)
    int2*  csr_sd  = (int2*)(ws + 5000004);     // 3,200,000 x 8B
    int*   spF_id  = (int*)(ws + 11400004);     // 25,000
    int*   spB_id  = (int*)(ws + 11425004);     // 25,000
    float* spF_v   = ws + 11450004;             // 400,000
    float* spB_v   = ws + 11850004;             // 400,000
    // transient overlays (dead before their hosts are written):
    int*   cnt     = (int*)(ws);                // in h region
    int*   cursor  = (int*)(ws + 100000);       // in h region
    int*   bsum    = (int*)(ws + 200000);       // in h region (512)
    int*   boff    = (int*)(ws + 200512);       // in h region (512)
    uint4* W1f     = (uint4*)(ws + 1600000);    // in ZSA region (dead before step 0)

    const int NB_SCAN = (N + 255) / 256;        // 391

    hipMemsetAsync(cnt, 0, (size_t)N * sizeof(int), stream);
    hist_kernel<<<(E + 255) / 256, 256, 0, stream>>>(dstp, cnt, E);
    dinv_kernel<<<(N + 255) / 256, 256, 0, stream>>>(cnt, dinv, N);
    scan1_kernel<<<NB_SCAN, 256, 0, stream>>>(cnt, row_st, bsum, N);
    scan2_kernel<<<1, 512, 0, stream>>>(bsum, boff, NB_SCAN);
    scan3_kernel<<<(N + 255) / 256, 256, 0, stream>>>(row_st, boff, cursor, N, E);
    scatter_kernel<<<(E + 255) / 256, 256, 0, stream>>>(srcp, dstp, cursor, csr_sd, E);
    w1_frag_kernel<<<64, 256, 0, stream>>>(W1, W1f);
    mlp_kernel<<<(N + 63) / 64, 256, 0, stream>>>(x, W1f, b1, W2, b2, dinv, h, ZSB, N);

    const int NPB = 25000;  // E / EB
    for (int k = 0; k < 10; ++k) {
        const int last = (k == 9) ? 1 : 0;
        const float* zin = (k == 0) ? ZSB : ((k & 1) ? ZSA : ZSB);
        float* zo = last ? (float*)d_out : ((k & 1) ? ZSB : ZSA);
        propA_kernel<<<NPB, 512, 0, stream>>>(csr_sd, row_st, dinv, zin, h, zo,
                                              spF_id, spB_id, spF_v, spB_v, last);
        propB_kernel<<<(N + 63) / 64, 256, 0, stream>>>(row_st, dinv, zin, h, zo,
                                                        spF_id, spB_id, spF_v, spB_v,
                                                        N, last);
    }
}

// Round 5
// 1473.957 us; speedup vs baseline: 1.1956x; 1.0993x over previous
//
#include <hip/hip_runtime.h>
#include <hip/hip_bf16.h>
#include <stdint.h>

#define N_NODES 100000
#define N_EDGES 3200000
#define ALPHA   0.1f
#define EB      128      // edges per propA block

typedef __attribute__((ext_vector_type(8))) short v8s;   // 8 x bf16
typedef __attribute__((ext_vector_type(4))) float f32x4; // MFMA acc

__device__ __forceinline__ uint32_t bf16_rne(float f) {
    uint32_t u = __float_as_uint(f);
    return (u + 0x7FFFu + ((u >> 16) & 1u)) >> 16;
}
__device__ __forceinline__ float bf16_f32(uint32_t b) { return __uint_as_float(b << 16); }

// ---------------------------------------------------------------------------
// W1 [256][512] fp32 -> A-fragment-ordered hi/lo bf16 chunks in global.
// ---------------------------------------------------------------------------
__global__ __launch_bounds__(256) void w1_frag_kernel(
    const float* __restrict__ W1, uint4* __restrict__ W1f)
{
    int tid = blockIdx.x * 256 + threadIdx.x;   // 16384
    int ks = tid >> 10, T = (tid >> 6) & 15, l = tid & 63;
    int row = T * 16 + (l & 15);
    int kb  = ks * 32 + (l >> 4) * 8;
    const float* src = W1 + (size_t)row * 512 + kb;
    float4 f0 = *(const float4*)(src);
    float4 f1 = *(const float4*)(src + 4);
    float f[8] = {f0.x, f0.y, f0.z, f0.w, f1.x, f1.y, f1.z, f1.w};
    uint32_t hi[8], lo[8];
#pragma unroll
    for (int j = 0; j < 8; ++j) {
        hi[j] = bf16_rne(f[j]);
        lo[j] = bf16_rne(f[j] - bf16_f32(hi[j]));
    }
    uint4 H = make_uint4(hi[0] | (hi[1] << 16), hi[2] | (hi[3] << 16),
                         hi[4] | (hi[5] << 16), hi[6] | (hi[7] << 16));
    uint4 L = make_uint4(lo[0] | (lo[1] << 16), lo[2] | (lo[3] << 16),
                         lo[4] | (lo[5] << 16), lo[6] | (lo[7] << 16));
    size_t base = ((size_t)(ks * 2) * 16 + T) * 64 + l;
    W1f[base]        = H;
    W1f[base + 1024] = L;   // p=1 plane
}

// ---------------------------------------------------------------------------
// MLP: h = relu(x@W1^T+b1)@W2^T+b2 via MFMA 16x16x32 bf16 hi/lo split.
// GEMM2 epilogue in 4-class chunks (16 live floats — R3's 64 spilled 410 MB).
// ---------------------------------------------------------------------------
__global__ __launch_bounds__(256, 2) void mlp_kernel(
    const float* __restrict__ x, const uint4* __restrict__ W1f,
    const float* __restrict__ b1, const float* __restrict__ W2,
    const float* __restrict__ b2, const float* __restrict__ dinv,
    float* __restrict__ h, float* __restrict__ hs, int n)
{
    __shared__ __align__(16) char smem[33280];
    char*  xs   = smem;                    // K-loop: hi plane 4096 + lo plane 4096
    float* W2s  = (float*)smem;            // epilogue: [16][260] = 16640 B
    float* part = (float*)(smem + 16640);  // epilogue: [4][64][16] = 16384 B

    const int tid = threadIdx.x;
    const int w = tid >> 6, l = tid & 63;
    const int l15 = l & 15, q = l >> 4;
    const int row0 = blockIdx.x * 64;

    const int s_l15 = tid & 15;
    const int s_seg = (tid >> 4) & 3;
    const int s_u   = tid >> 6;
    const int s_grow = row0 + s_u * 16 + s_l15;

    f32x4 acc[4][4];
#pragma unroll
    for (int mt = 0; mt < 4; ++mt)
#pragma unroll
        for (int nt = 0; nt < 4; ++nt) acc[mt][nt] = (f32x4){0.f, 0.f, 0.f, 0.f};

    for (int ks = 0; ks < 16; ++ks) {
        uint4 aHu[4], aLu[4];
#pragma unroll
        for (int mt = 0; mt < 4; ++mt) {
            size_t cidx = ((size_t)(ks * 2) * 16 + (w * 4 + mt)) * 64 + l;
            aHu[mt] = W1f[cidx];
            aLu[mt] = W1f[cidx + 1024];
        }
        float4 f0 = make_float4(0.f, 0.f, 0.f, 0.f), f1 = f0;
        if (s_grow < n) {
            const float* xp = x + (size_t)s_grow * 512 + ks * 32 + s_seg * 8;
            f0 = *(const float4*)(xp);
            f1 = *(const float4*)(xp + 4);
        }
        float f[8] = {f0.x, f0.y, f0.z, f0.w, f1.x, f1.y, f1.z, f1.w};
        uint32_t hi[8], lo[8];
#pragma unroll
        for (int j = 0; j < 8; ++j) {
            hi[j] = bf16_rne(f[j]);
            lo[j] = bf16_rne(f[j] - bf16_f32(hi[j]));
        }
        uint4 H = make_uint4(hi[0] | (hi[1] << 16), hi[2] | (hi[3] << 16),
                             hi[4] | (hi[5] << 16), hi[6] | (hi[7] << 16));
        uint4 L = make_uint4(lo[0] | (lo[1] << 16), lo[2] | (lo[3] << 16),
                             lo[4] | (lo[5] << 16), lo[6] | (lo[7] << 16));
        __syncthreads();
        *(uint4*)(xs +        s_u * 1024 + (s_seg * 16 + s_l15) * 16) = H;
        *(uint4*)(xs + 4096 + s_u * 1024 + (s_seg * 16 + s_l15) * 16) = L;
        __syncthreads();

        v8s bH[4], bL[4];
#pragma unroll
        for (int nt = 0; nt < 4; ++nt) {
            bH[nt] = *(v8s*)(xs +        nt * 1024 + l * 16);
            bL[nt] = *(v8s*)(xs + 4096 + nt * 1024 + l * 16);
        }
#pragma unroll
        for (int mt = 0; mt < 4; ++mt) {
            v8s aH = *(v8s*)&aHu[mt];
            v8s aL = *(v8s*)&aLu[mt];
#pragma unroll
            for (int nt = 0; nt < 4; ++nt) {
                f32x4 c = acc[mt][nt];
                c = __builtin_amdgcn_mfma_f32_16x16x32_bf16(aH, bH[nt], c, 0, 0, 0);
                c = __builtin_amdgcn_mfma_f32_16x16x32_bf16(aH, bL[nt], c, 0, 0, 0);
                c = __builtin_amdgcn_mfma_f32_16x16x32_bf16(aL, bH[nt], c, 0, 0, 0);
                acc[mt][nt] = c;
            }
        }
    }

#pragma unroll
    for (int mt = 0; mt < 4; ++mt) {
        float4 bv = *(const float4*)(b1 + w * 64 + mt * 16 + q * 4);
#pragma unroll
        for (int nt = 0; nt < 4; ++nt) {
            acc[mt][nt][0] = fmaxf(acc[mt][nt][0] + bv.x, 0.f);
            acc[mt][nt][1] = fmaxf(acc[mt][nt][1] + bv.y, 0.f);
            acc[mt][nt][2] = fmaxf(acc[mt][nt][2] + bv.z, 0.f);
            acc[mt][nt][3] = fmaxf(acc[mt][nt][3] + bv.w, 0.f);
        }
    }

    __syncthreads();
    {
        int c = tid >> 4, k16 = (tid & 15) * 16;
#pragma unroll
        for (int i = 0; i < 4; ++i)
            *(float4*)(W2s + c * 260 + k16 + i * 4) =
                *(const float4*)(W2 + c * 256 + k16 + i * 4);
    }
    __syncthreads();

#pragma unroll
    for (int c4 = 0; c4 < 4; ++c4) {
        float p2[4][4];
#pragma unroll
        for (int nt = 0; nt < 4; ++nt)
#pragma unroll
            for (int cc = 0; cc < 4; ++cc) p2[nt][cc] = 0.f;
#pragma unroll
        for (int mt = 0; mt < 4; ++mt)
#pragma unroll
            for (int cc = 0; cc < 4; ++cc) {
                float4 wv = *(float4*)(W2s + (c4 * 4 + cc) * 260 + w * 64 + mt * 16 + q * 4);
#pragma unroll
                for (int nt = 0; nt < 4; ++nt)
                    p2[nt][cc] += acc[mt][nt][0] * wv.x + acc[mt][nt][1] * wv.y +
                                  acc[mt][nt][2] * wv.z + acc[mt][nt][3] * wv.w;
            }
#pragma unroll
        for (int nt = 0; nt < 4; ++nt)
#pragma unroll
            for (int cc = 0; cc < 4; ++cc) {
                p2[nt][cc] += __shfl_xor(p2[nt][cc], 16);
                p2[nt][cc] += __shfl_xor(p2[nt][cc], 32);
            }
        if (q == c4) {
#pragma unroll
            for (int nt = 0; nt < 4; ++nt)
                *(float4*)(part + ((w * 64 + nt * 16 + l15) << 4) + c4 * 4) =
                    make_float4(p2[nt][0], p2[nt][1], p2[nt][2], p2[nt][3]);
        }
    }
    __syncthreads();
    {
        int node = tid >> 2, c4 = (tid & 3) * 4;
        float4 s = make_float4(0.f, 0.f, 0.f, 0.f);
#pragma unroll
        for (int ww = 0; ww < 4; ++ww) {
            float4 v = *(float4*)(part + ((ww * 64 + node) << 4) + c4);
            s.x += v.x; s.y += v.y; s.z += v.z; s.w += v.w;
        }
        float4 bv = *(const float4*)(b2 + c4);
        int grow = row0 + node;
        if (grow < n) {
            float4 hv = make_float4(s.x + bv.x, s.y + bv.y, s.z + bv.z, s.w + bv.w);
            *(float4*)(h + (size_t)grow * 16 + c4) = hv;
            float di = dinv[grow];
            *(float4*)(hs + (size_t)grow * 16 + c4) =
                make_float4(di * hv.x, di * hv.y, di * hv.z, di * hv.w);
        }
    }
}

// ---------------------------------------------------------------------------
// CSR build
// ---------------------------------------------------------------------------
__global__ void hist_kernel(const int* __restrict__ dst, int* __restrict__ cnt, int e)
{
    int i = blockIdx.x * blockDim.x + threadIdx.x;
    if (i < e) atomicAdd(&cnt[dst[i]], 1);
}

__global__ void dinv_kernel(const int* __restrict__ cnt, float* __restrict__ dinv, int n)
{
    int i = blockIdx.x * blockDim.x + threadIdx.x;
    if (i < n) dinv[i] = rsqrtf((float)cnt[i] + 1.0f);  // +1 self-loop
}

// multi-block exclusive scan (3 phases)
__global__ __launch_bounds__(256) void scan1_kernel(
    const int* __restrict__ cnt, int* __restrict__ row_loc,
    int* __restrict__ bsum, int n)
{
    __shared__ int sm[256];
    int i = blockIdx.x * 256 + threadIdx.x;
    int v = (i < n) ? cnt[i] : 0;
    sm[threadIdx.x] = v;
    __syncthreads();
#pragma unroll
    for (int off = 1; off < 256; off <<= 1) {
        int t = (threadIdx.x >= off) ? sm[threadIdx.x - off] : 0;
        __syncthreads();
        sm[threadIdx.x] += t;
        __syncthreads();
    }
    if (i < n) row_loc[i] = sm[threadIdx.x] - v;
    if (threadIdx.x == 255) bsum[blockIdx.x] = sm[255];
}

__global__ __launch_bounds__(512) void scan2_kernel(
    const int* __restrict__ bsum, int* __restrict__ boff, int nb)
{
    __shared__ int sm[512];
    int i = threadIdx.x;
    int v = (i < nb) ? bsum[i] : 0;
    sm[i] = v;
    __syncthreads();
#pragma unroll
    for (int off = 1; off < 512; off <<= 1) {
        int t = (i >= off) ? sm[i - off] : 0;
        __syncthreads();
        sm[i] += t;
        __syncthreads();
    }
    if (i < nb) boff[i] = sm[i] - v;
}

__global__ void scan3_kernel(int* __restrict__ row_st, const int* __restrict__ boff,
                             int* __restrict__ cursor, int n, int e)
{
    int i = blockIdx.x * blockDim.x + threadIdx.x;
    if (i < n) {
        int r = row_st[i] + boff[i >> 8];
        row_st[i] = r;
        cursor[i] = r;
    }
    if (i == 0) row_st[n] = e;
}

// ---------------------------------------------------------------------------
// XCD-windowed scatter: block b = chunk (b>>3) x dst-window (b&7).
// All writers of a 12500-node window (3.2 MB of csr_sd) land on one XCD
// (round-robin blockIdx%8 placement) -> 64B lines fully dirtied while
// L2-resident -> ~1 writeback per line instead of 1 per 8B store (R4:
// WRITE_SIZE 198 MB = 64B x E). Re-reads of ei are L2/L3-absorbed.
// ---------------------------------------------------------------------------
#define SC_CHUNK 2048
__global__ __launch_bounds__(256) void scatter8_kernel(
    const int* __restrict__ src, const int* __restrict__ dst,
    int* __restrict__ cursor, int2* __restrict__ csr_sd, int e)
{
    const int w    = blockIdx.x & 7;
    const int base = (blockIdx.x >> 3) * SC_CHUNK;
    const int wlo  = w * (N_NODES / 8);
    const int whi  = wlo + (N_NODES / 8);
#pragma unroll
    for (int t = 0; t < SC_CHUNK / 256; ++t) {
        int i = base + t * 256 + threadIdx.x;
        if (i < e) {
            int d = dst[i];
            if (d >= wlo && d < whi) {
                int s = src[i];
                int pos = atomicAdd(&cursor[d], 1);
                csr_sd[pos] = make_int2(s, d);
            }
        }
    }
}

// ---------------------------------------------------------------------------
// Propagation, edge-parallel, atomic-free. zs = dinv*z flows between steps.
// ---------------------------------------------------------------------------
__device__ __forceinline__ void finalize_node(
    int d, float4 S, const float* dinv, const float* zs_in, const float* hmat,
    float* out, int f4, int is_last)
{
    float di = dinv[d];
    const float4 self = *(const float4*)(zs_in + (size_t)d * 16 + f4);
    const float4 hv   = *(const float4*)(hmat + (size_t)d * 16 + f4);
    float4 zn;
    zn.x = fmaf(1.0f - ALPHA, di * (S.x + self.x), ALPHA * hv.x);
    zn.y = fmaf(1.0f - ALPHA, di * (S.y + self.y), ALPHA * hv.y);
    zn.z = fmaf(1.0f - ALPHA, di * (S.z + self.z), ALPHA * hv.z);
    zn.w = fmaf(1.0f - ALPHA, di * (S.w + self.w), ALPHA * hv.w);
    if (!is_last) {
        *(float4*)(out + (size_t)d * 16 + f4) =
            make_float4(di * zn.x, di * zn.y, di * zn.z, di * zn.w);
    } else {
        float m = fmaxf(fmaxf(zn.x, zn.y), fmaxf(zn.z, zn.w));
        m = fmaxf(m, __shfl_xor(m, 1));
        m = fmaxf(m, __shfl_xor(m, 2));
        float ss = expf(zn.x - m) + expf(zn.y - m) + expf(zn.z - m) + expf(zn.w - m);
        ss += __shfl_xor(ss, 1);
        ss += __shfl_xor(ss, 2);
        float ls = logf(ss);
        *(float4*)(out + (size_t)d * 16 + f4) =
            make_float4(zn.x - m - ls, zn.y - m - ls, zn.z - m - ls, zn.w - m - ls);
    }
}

__global__ __launch_bounds__(512) void propA_kernel(
    const int2* __restrict__ csr_sd, const int* __restrict__ row_st,
    const float* __restrict__ dinv, const float* __restrict__ zs_in,
    const float* __restrict__ hmat, float* __restrict__ out,
    int* __restrict__ spF_id, int* __restrict__ spB_id,
    float* __restrict__ spF_v, float* __restrict__ spB_v, int is_last)
{
    __shared__ float sc[EB * 16];   // 8 KB contributions
    const int tid = threadIdx.x;
    const int quad = tid >> 2;
    const int f4 = (tid & 3) * 4;
    const int blk_lo = blockIdx.x * EB;
    const int j = blk_lo + quad;

    int d = -1;
    float4 c4 = make_float4(0.f, 0.f, 0.f, 0.f);
    if (j < N_EDGES) {
        int2 sd = csr_sd[j];
        d = sd.y;
        c4 = *(const float4*)(zs_in + (size_t)sd.x * 16 + f4);
    }
    *(float4*)(sc + quad * 16 + f4) = c4;
    __syncthreads();
    if (j >= N_EDGES) return;

    const int rs = row_st[d];
    const bool is_start = (quad == 0) || (j == rs);
    if (!is_start) return;

    const int re = row_st[d + 1];
    const int kend = min(re - blk_lo, EB);
    float4 S = c4;
    for (int k = quad + 1; k < kend; ++k) {
        S.x += sc[k * 16 + f4 + 0];
        S.y += sc[k * 16 + f4 + 1];
        S.z += sc[k * 16 + f4 + 2];
        S.w += sc[k * 16 + f4 + 3];
    }
    const int run_e = blk_lo + kend;
    const bool full = (j == rs) && (run_e == re);
    const bool first_run = (quad == 0);
    const bool last_run  = (kend == EB) || (run_e == N_EDGES);

    if (full)
        finalize_node(d, S, dinv, zs_in, hmat, out, f4, is_last);

    if (first_run) {
        if ((tid & 3) == 0) {
            spF_id[blockIdx.x] = full ? -1 : d;
            if (last_run) spB_id[blockIdx.x] = -1;
        }
        if (!full) *(float4*)(spF_v + blockIdx.x * 16 + f4) = S;
    } else if (last_run) {
        if ((tid & 3) == 0) spB_id[blockIdx.x] = full ? -1 : d;
        if (!full) *(float4*)(spB_v + blockIdx.x * 16 + f4) = S;
    }
}

__global__ __launch_bounds__(256) void propB_kernel(
    const int* __restrict__ row_st, const float* __restrict__ dinv,
    const float* __restrict__ zs_in, const float* __restrict__ hmat,
    float* __restrict__ out,
    const int* __restrict__ spF_id, const int* __restrict__ spB_id,
    const float* __restrict__ spF_v, const float* __restrict__ spB_v,
    int n, int is_last)
{
    const int d = blockIdx.x * 64 + (threadIdx.x >> 2);
    const int f4 = (threadIdx.x & 3) * 4;
    if (d >= n) return;
    const int rs = row_st[d], re = row_st[d + 1];
    const bool crossing = (rs == re) || ((rs >> 7) != ((re - 1) >> 7));
    if (!crossing) return;
    float4 S = make_float4(0.f, 0.f, 0.f, 0.f);
    if (re > rs) {
        const int b0 = rs >> 7, b1 = (re - 1) >> 7;
        for (int b = b0; b <= b1; ++b) {
            if (spF_id[b] == d) {
                S.x += spF_v[b * 16 + f4 + 0]; S.y += spF_v[b * 16 + f4 + 1];
                S.z += spF_v[b * 16 + f4 + 2]; S.w += spF_v[b * 16 + f4 + 3];
            }
            if (spB_id[b] == d) {
                S.x += spB_v[b * 16 + f4 + 0]; S.y += spB_v[b * 16 + f4 + 1];
                S.z += spB_v[b * 16 + f4 + 2]; S.w += spB_v[b * 16 + f4 + 3];
            }
        }
    }
    finalize_node(d, S, dinv, zs_in, hmat, out, f4, is_last);
}

// ---------------------------------------------------------------------------
extern "C" void kernel_launch(void* const* d_in, const int* in_sizes, int n_in,
                              void* d_out, int out_size, void* d_ws, size_t ws_size,
                              hipStream_t stream)
{
    const float* x  = (const float*)d_in[0];
    const float* W1 = (const float*)d_in[1];
    const float* b1 = (const float*)d_in[2];
    const float* W2 = (const float*)d_in[3];
    const float* b2 = (const float*)d_in[4];
    const int*   ei = (const int*)d_in[5];

    const int N = N_NODES;
    const int E = N_EDGES;
    const int* srcp = ei;
    const int* dstp = ei + E;

    float* ws = (float*)d_ws;
    float* h       = ws;                        // 1,600,000 f
    float* ZSA     = ws + 1600000;              // 1,600,000 f
    float* ZSB     = ws + 3200000;              // 1,600,000 f  (starts as hs)
    float* dinv    = ws + 4800000;              // 100,000 f
    int*   row_st  = (int*)(ws + 4900000);      // 100,001 i (pad 100004)
    int2*  csr_sd  = (int2*)(ws + 5000004);     // 3,200,000 x 8B
    int*   spF_id  = (int*)(ws + 11400004);     // 25,000
    int*   spB_id  = (int*)(ws + 11425004);     // 25,000
    float* spF_v   = ws + 11450004;             // 400,000
    float* spB_v   = ws + 11850004;             // 400,000
    // transient overlays:
    int*   cnt     = (int*)(ws);                // in h region
    int*   cursor  = (int*)(ws + 100000);       // in h region
    int*   bsum    = (int*)(ws + 200000);       // in h region (512)
    int*   boff    = (int*)(ws + 200512);       // in h region (512)
    uint4* W1f     = (uint4*)(ws + 1600000);    // in ZSA region (dead before step 0)

    const int NB_SCAN = (N + 255) / 256;        // 391

    hipMemsetAsync(cnt, 0, (size_t)N * sizeof(int), stream);
    hist_kernel<<<(E + 255) / 256, 256, 0, stream>>>(dstp, cnt, E);
    dinv_kernel<<<(N + 255) / 256, 256, 0, stream>>>(cnt, dinv, N);
    scan1_kernel<<<NB_SCAN, 256, 0, stream>>>(cnt, row_st, bsum, N);
    scan2_kernel<<<1, 512, 0, stream>>>(bsum, boff, NB_SCAN);
    scan3_kernel<<<(N + 255) / 256, 256, 0, stream>>>(row_st, boff, cursor, N, E);
    {
        const int nchunks = (E + SC_CHUNK - 1) / SC_CHUNK;   // 1563
        scatter8_kernel<<<nchunks * 8, 256, 0, stream>>>(srcp, dstp, cursor, csr_sd, E);
    }
    w1_frag_kernel<<<64, 256, 0, stream>>>(W1, W1f);
    mlp_kernel<<<(N + 63) / 64, 256, 0, stream>>>(x, W1f, b1, W2, b2, dinv, h, ZSB, N);

    const int NPB = 25000;  // E / EB
    for (int k = 0; k < 10; ++k) {
        const int last = (k == 9) ? 1 : 0;
        const float* zin = (k == 0) ? ZSB : ((k & 1) ? ZSA : ZSB);
        float* zo = last ? (float*)d_out : ((k & 1) ? ZSB : ZSA);
        propA_kernel<<<NPB, 512, 0, stream>>>(csr_sd, row_st, dinv, zin, h, zo,
                                              spF_id, spB_id, spF_v, spB_v, last);
        propB_kernel<<<(N + 63) / 64, 256, 0, stream>>>(row_st, dinv, zin, h, zo,
                                                        spF_id, spB_id, spF_v, spB_v,
                                                        N, last);
    }
}